// Round 1
// baseline (1947.078 us; speedup 1.0000x reference)
//
#include <hip/hip_runtime.h>

#define B 128
#define T 1500
#define NI 80        // N_MELS
#define H 128        // HIDDEN
#define G 384        // 3*H
#define TT 32        // t-tile for gx gemm

__device__ __forceinline__ float sigf(float x) { return 1.0f / (1.0f + __expf(-x)); }
__device__ __forceinline__ float tanhfast(float x) { return 1.0f - 2.0f / (1.0f + __expf(2.0f * x)); }

// gx[tl][b][g] = b_ih[g] + sum_i x[b, t0+tl, i] * w_ih[g, i]
__global__ __launch_bounds__(384)
void gx_gemm_kernel(const float* __restrict__ x, const float* __restrict__ w_ih,
                    const float* __restrict__ b_ih, float* __restrict__ gx,
                    int t0, int ct) {
    int ntiles = (ct + TT - 1) / TT;
    int b = blockIdx.x / ntiles;
    int tile = blockIdx.x % ntiles;
    int tl0 = tile * TT;
    int n = (ct - tl0 < TT) ? (ct - tl0) : TT;
    int tid = threadIdx.x;  // = output g

    __shared__ __align__(16) float xs[TT * NI];
    const float* xsrc = x + ((size_t)b * T + (size_t)(t0 + tl0)) * NI;
    for (int idx = tid; idx < n * NI; idx += 384) xs[idx] = xsrc[idx];

    float4 w[20];
    const float4* wrow = (const float4*)(w_ih + (size_t)tid * NI);
#pragma unroll
    for (int i = 0; i < 20; ++i) w[i] = wrow[i];
    float bias = b_ih[tid];
    __syncthreads();

    float* gout = gx + ((size_t)tl0 * B + b) * G + tid;
    for (int tt = 0; tt < n; ++tt) {
        const float4* xv = (const float4*)(xs + tt * NI);
        float a0 = 0.f, a1 = 0.f, a2 = 0.f, a3 = 0.f;
#pragma unroll
        for (int i = 0; i < 20; ++i) {
            float4 xvi = xv[i];
            a0 = fmaf(w[i].x, xvi.x, a0);
            a1 = fmaf(w[i].y, xvi.y, a1);
            a2 = fmaf(w[i].z, xvi.z, a2);
            a3 = fmaf(w[i].w, xvi.w, a3);
        }
        gout[(size_t)tt * B * G] = bias + ((a0 + a1) + (a2 + a3));
    }
}

// One block per batch element. 512 threads: tid = j*4 + q, j in [0,128) hidden unit,
// q in [0,4) k-quarter. Thread holds W_hh rows {j, j+H, j+2H} slice k in [32q,32q+32).
// h lives in LDS (double-buffered, padded 4 floats per 32 so q-groups are bank-disjoint).
__global__ __launch_bounds__(512)
void scan_kernel(const float* __restrict__ gx, const float* __restrict__ w_hh,
                 const float* __restrict__ b_hh, float* __restrict__ h_state,
                 int ct, int first, int last,
                 const float* __restrict__ x,
                 const float* __restrict__ w_ih_b, const float* __restrict__ b_ih_b,
                 const float* __restrict__ b_hh_b,
                 const float* __restrict__ w1, const float* __restrict__ b1,
                 const float* __restrict__ w2, const float* __restrict__ b2,
                 float* __restrict__ out) {
    int b = blockIdx.x;
    int tid = threadIdx.x;
    int j = tid >> 2;
    int q = tid & 3;

    __shared__ __align__(16) float hs[2][144];      // 128 + 4-per-32 padding
    __shared__ __align__(16) float tail_gx[G];
    __shared__ __align__(16) float last_s[2 * H];
    __shared__ __align__(16) float xb_s[NI];
    __shared__ __align__(16) float hdn_s[64];
    (void)hdn_s;

    float4 wr[8], wz[8], wn[8];
    {
        const float4* pr = (const float4*)(w_hh + (size_t)j * H + 32 * q);
        const float4* pz = (const float4*)(w_hh + (size_t)(j + H) * H + 32 * q);
        const float4* pn = (const float4*)(w_hh + (size_t)(j + 2 * H) * H + 32 * q);
#pragma unroll
        for (int i = 0; i < 8; ++i) { wr[i] = pr[i]; wz[i] = pz[i]; wn[i] = pn[i]; }
    }
    float br = b_hh[j], bz = b_hh[j + H], bn = b_hh[j + 2 * H];

    int jpad = j + ((j >> 5) << 2);  // padded LDS index for h[j]
    float h_cur = 0.f;
    float gx0 = 0.f, gx1 = 0.f, gx2 = 0.f;
    if (q == 0) {
        if (!first) h_cur = h_state[b * H + j];
        hs[0][jpad] = h_cur;
        const float* gp = gx + (size_t)b * G;
        gx0 = gp[j]; gx1 = gp[j + H]; gx2 = gp[j + 2 * H];
    }
    __syncthreads();

    for (int tl = 0; tl < ct; ++tl) {
        int cur = tl & 1;
        const float4* hv4 = ((const float4*)hs[cur]) + 9 * q;  // 36q floats = 9q float4
        float ar = 0.f, az = 0.f, an = 0.f;
#pragma unroll
        for (int i = 0; i < 8; ++i) {
            float4 hv = hv4[i];
            ar = fmaf(wr[i].x, hv.x, ar); az = fmaf(wz[i].x, hv.x, az); an = fmaf(wn[i].x, hv.x, an);
            ar = fmaf(wr[i].y, hv.y, ar); az = fmaf(wz[i].y, hv.y, az); an = fmaf(wn[i].y, hv.y, an);
            ar = fmaf(wr[i].z, hv.z, ar); az = fmaf(wz[i].z, hv.z, az); an = fmaf(wn[i].z, hv.z, an);
            ar = fmaf(wr[i].w, hv.w, ar); az = fmaf(wz[i].w, hv.w, az); an = fmaf(wn[i].w, hv.w, an);
        }
        float gxn0 = 0.f, gxn1 = 0.f, gxn2 = 0.f;
        bool pf = (q == 0) && (tl + 1 < ct);
        if (pf) {
            const float* gp = gx + ((size_t)(tl + 1) * B + b) * G;
            gxn0 = gp[j]; gxn1 = gp[j + H]; gxn2 = gp[j + 2 * H];
        }
        // quad reduce (DPP, stays on VALU pipe)
        ar += __shfl_xor(ar, 1); ar += __shfl_xor(ar, 2);
        az += __shfl_xor(az, 1); az += __shfl_xor(az, 2);
        an += __shfl_xor(an, 1); an += __shfl_xor(an, 2);
        if (q == 0) {
            float r = sigf(gx0 + br + ar);
            float z = sigf(gx1 + bz + az);
            float n = tanhfast(gx2 + r * (bn + an));
            h_cur = (1.f - z) * n + z * h_cur;
            hs[cur ^ 1][jpad] = h_cur;
            gx0 = gxn0; gx1 = gxn1; gx2 = gxn2;
        }
        __syncthreads();
    }

    if (!last) {
        if (q == 0) h_state[b * H + j] = h_cur;
        return;
    }

    // ---- backward single step (h0 = 0) + MLP head ----
    if (tid < NI) xb_s[tid] = x[((size_t)b * T + (T - 1)) * NI + tid];
    if (q == 0) last_s[j] = h_cur;  // forward final hidden
    __syncthreads();

    if (tid < G) {
        const float4* wbr = (const float4*)(w_ih_b + (size_t)tid * NI);
        const float4* xv = (const float4*)xb_s;
        float a0 = 0.f, a1 = 0.f, a2 = 0.f, a3 = 0.f;
#pragma unroll
        for (int i = 0; i < 20; ++i) {
            float4 wv = wbr[i]; float4 x4 = xv[i];
            a0 = fmaf(wv.x, x4.x, a0); a1 = fmaf(wv.y, x4.y, a1);
            a2 = fmaf(wv.z, x4.z, a2); a3 = fmaf(wv.w, x4.w, a3);
        }
        tail_gx[tid] = b_ih_b[tid] + ((a0 + a1) + (a2 + a3));
    }
    __syncthreads();

    if (tid < H) {
        float r = sigf(tail_gx[tid] + b_hh_b[tid]);
        float z = sigf(tail_gx[tid + H] + b_hh_b[tid + H]);
        float n = tanhfast(tail_gx[tid + 2 * H] + r * b_hh_b[tid + 2 * H]);
        last_s[H + tid] = (1.f - z) * n;  // + z*0
    }
    __syncthreads();

    if (tid < 64) {
        const float4* w1r = (const float4*)(w1 + (size_t)tid * 2 * H);
        const float4* lv = (const float4*)last_s;
        float a0 = 0.f, a1 = 0.f, a2 = 0.f, a3 = 0.f;
#pragma unroll
        for (int i = 0; i < 64; ++i) {
            float4 wv = w1r[i]; float4 l4 = lv[i];
            a0 = fmaf(wv.x, l4.x, a0); a1 = fmaf(wv.y, l4.y, a1);
            a2 = fmaf(wv.z, l4.z, a2); a3 = fmaf(wv.w, l4.w, a3);
        }
        float v = b1[tid] + ((a0 + a1) + (a2 + a3));
        v = fmaxf(v, 0.f) * w2[tid];
#pragma unroll
        for (int off = 32; off > 0; off >>= 1) v += __shfl_down(v, off);
        if (tid == 0) out[b] = v + b2[0];
    }
}

extern "C" void kernel_launch(void* const* d_in, const int* in_sizes, int n_in,
                              void* d_out, int out_size, void* d_ws, size_t ws_size,
                              hipStream_t stream) {
    (void)in_sizes; (void)n_in; (void)out_size;
    const float* x      = (const float*)d_in[0];
    const float* w_ih_f = (const float*)d_in[1];
    const float* w_hh_f = (const float*)d_in[2];
    const float* b_ih_f = (const float*)d_in[3];
    const float* b_hh_f = (const float*)d_in[4];
    const float* w_ih_b = (const float*)d_in[5];
    const float* w_hh_b = (const float*)d_in[6];  // unused: h0=0 makes gh_b = b_hh_b
    const float* b_ih_b = (const float*)d_in[7];
    const float* b_hh_b = (const float*)d_in[8];
    const float* w1     = (const float*)d_in[9];
    const float* b1     = (const float*)d_in[10];
    const float* w2     = (const float*)d_in[11];
    const float* b2     = (const float*)d_in[12];
    (void)w_hh_b;
    float* out = (float*)d_out;

    float* h_state = (float*)d_ws;                 // B*H floats
    float* gxbuf = h_state + B * H;
    size_t hbytes = (size_t)B * H * sizeof(float);
    size_t avail = ws_size > hbytes ? ws_size - hbytes : 0;
    long long chunkT = (long long)(avail / ((size_t)B * G * sizeof(float)));
    if (chunkT > T) chunkT = T;
    if (chunkT < 1) chunkT = 1;

    for (int t0 = 0; t0 < T; t0 += (int)chunkT) {
        int ct = (T - t0 < (int)chunkT) ? (T - t0) : (int)chunkT;
        int ntiles = (ct + TT - 1) / TT;
        gx_gemm_kernel<<<dim3(B * ntiles), dim3(384), 0, stream>>>(
            x, w_ih_f, b_ih_f, gxbuf, t0, ct);
        scan_kernel<<<dim3(B), dim3(512), 0, stream>>>(
            gxbuf, w_hh_f, b_hh_f, h_state, ct,
            (t0 == 0) ? 1 : 0, (t0 + ct >= T) ? 1 : 0,
            x, w_ih_b, b_ih_b, b_hh_b, w1, b1, w2, b2, out);
    }
}